// Round 3
// baseline (10020.775 us; speedup 1.0000x reference)
//
#include <hip/hip_runtime.h>
#include <hip/hip_bf16.h>

__device__ __forceinline__ float sigmoidf_(float x) {
    return 1.0f / (1.0f + __expf(-x));
}
__device__ __forceinline__ float tanhf_(float x) {
    float e = __expf(2.0f * x);
    return 1.0f - 2.0f / (e + 1.0f);
}
__device__ __forceinline__ float f4c(const float4& v, int q) {
    return q == 0 ? v.x : q == 1 ? v.y : q == 2 ? v.z : v.w;
}

// ---------------------------------------------------------------------------
// Kernel 1: G[node, 0..95] = h[node] @ Wih.T + bih
// ---------------------------------------------------------------------------
__global__ __launch_bounds__(256) void precompute_gi(
    const float* __restrict__ h, const float* __restrict__ Wih,
    const float* __restrict__ bih, float* __restrict__ G, int n1)
{
    int node = blockIdx.x * 256 + threadIdx.x;
    if (node >= n1) return;
    float x[32];
    const float4* hx = (const float4*)(h + (size_t)node * 32);
#pragma unroll
    for (int c = 0; c < 8; ++c) {
        float4 v = hx[c];
        x[c*4+0] = v.x; x[c*4+1] = v.y; x[c*4+2] = v.z; x[c*4+3] = v.w;
    }
    float* grow = G + (size_t)node * 96;
#pragma unroll
    for (int jb = 0; jb < 24; ++jb) {
        float acc[4];
#pragma unroll
        for (int q = 0; q < 4; ++q) {
            int j = jb * 4 + q;
            float a = bih[j];
#pragma unroll
            for (int i = 0; i < 32; ++i)
                a += x[i] * Wih[j * 32 + i];
            acc[q] = a;
        }
        *(float4*)(grow + jb * 4) = make_float4(acc[0], acc[1], acc[2], acc[3]);
    }
}

// ---------------------------------------------------------------------------
// CSR build kernels
// ---------------------------------------------------------------------------
__global__ __launch_bounds__(256) void hist_kernel(
    const int* __restrict__ flat_idx, int nI, int* __restrict__ count)
{
    int i = blockIdx.x * 256 + threadIdx.x;
    if (i < nI) atomicAdd(&count[flat_idx[i]], 1);
}

__global__ __launch_bounds__(256) void scan_block(
    const int* __restrict__ count, int* __restrict__ incl,
    int* __restrict__ bsums, int n)
{
    __shared__ int s[256];
    int i = blockIdx.x * 256 + threadIdx.x;
    int v = (i < n) ? count[i] : 0;
    s[threadIdx.x] = v;
    __syncthreads();
    for (int d = 1; d < 256; d <<= 1) {
        int t = (threadIdx.x >= d) ? s[threadIdx.x - d] : 0;
        __syncthreads();
        s[threadIdx.x] += t;
        __syncthreads();
    }
    if (i < n) incl[i] = s[threadIdx.x];
    if (threadIdx.x == 255) bsums[blockIdx.x] = s[255];
}

__global__ __launch_bounds__(1024) void scan_bsums(int* bsums, int nb)
{
    __shared__ int s[1024];
    int v = (threadIdx.x < nb) ? bsums[threadIdx.x] : 0;
    s[threadIdx.x] = v;
    __syncthreads();
    for (int d = 1; d < 1024; d <<= 1) {
        int t = (threadIdx.x >= d) ? s[threadIdx.x - d] : 0;
        __syncthreads();
        s[threadIdx.x] += t;
        __syncthreads();
    }
    if (threadIdx.x < nb) bsums[threadIdx.x] = s[threadIdx.x] - v; // exclusive
}

__global__ __launch_bounds__(256) void finalize_offs(
    const int* __restrict__ incl, const int* __restrict__ bsums,
    int* __restrict__ offs, int n)
{
    int i = blockIdx.x * 256 + threadIdx.x;
    if (i < n) offs[i + 1] = incl[i] + bsums[blockIdx.x];
    if (i == 0) offs[0] = 0;
}

__global__ __launch_bounds__(256) void fill_entries(
    const int* __restrict__ flat_idx, int nI,
    int* __restrict__ cursor, int* __restrict__ entries)
{
    int i = blockIdx.x * 256 + threadIdx.x;
    if (i >= nI) return;
    int n = flat_idx[i];
    int p = atomicAdd(&cursor[n], 1);
    entries[p] = i;
}

// ---------------------------------------------------------------------------
// Fused gather(+recompute) + MLP. One thread per node.
// For each CSR entry i = e*K + t of this node, recompute the edge's GRU
// chain s=0..t from G (input gates) and fold the final hv into acc via the
// matching W1 block. GRU math is identical to the scatter version.
// ---------------------------------------------------------------------------
template <int K>
__device__ __forceinline__ void seg_fold(
    const int* __restrict__ idx,
    const int* __restrict__ offs, const int* __restrict__ ent,
    int node, const float* __restrict__ G,
    const float* __restrict__ Whh, const float* __restrict__ bhh,
    const float* __restrict__ W1blk,   // W1 + m*32 (row stride 128)
    float acc[32])
{
    int beg = offs[node], end = offs[node + 1];
    for (int p = beg; p < end; ++p) {
        int i = ent[p];
        int e = i / K;
        int t = i - e * K;
        float hv[32];
        for (int s = 0; s <= t; ++s) {
            int nd = idx[e * K + s];
            const float* grow = G + (size_t)nd * 96;
            float hn[32];
#pragma unroll
            for (int jb = 0; jb < 8; ++jb) {
                float4 gr4 = *(const float4*)(grow + jb * 4);
                float4 gz4 = *(const float4*)(grow + 32 + jb * 4);
                float4 gn4 = *(const float4*)(grow + 64 + jb * 4);
#pragma unroll
                for (int q = 0; q < 4; ++q) {
                    int j = jb * 4 + q;
                    float ir = f4c(gr4, q), iz = f4c(gz4, q), in_ = f4c(gn4, q);
                    float hr = bhh[j], hz = bhh[32 + j], hn2 = bhh[64 + j];
                    if (s > 0) {
#pragma unroll
                        for (int ii = 0; ii < 32; ++ii) {
                            hr  += hv[ii] * Whh[j * 32 + ii];
                            hz  += hv[ii] * Whh[(32 + j) * 32 + ii];
                            hn2 += hv[ii] * Whh[(64 + j) * 32 + ii];
                        }
                    }
                    float r = sigmoidf_(ir + hr);
                    float z = sigmoidf_(iz + hz);
                    float n = tanhf_(in_ + r * hn2);
                    hn[j] = (s > 0) ? ((1.0f - z) * n + z * hv[j]) : (1.0f - z) * n;
                }
            }
#pragma unroll
            for (int j = 0; j < 32; ++j) hv[j] = hn[j];
        }
        // fold hv into MLP pre-activation via this k's W1 block
#pragma unroll
        for (int j = 0; j < 32; ++j) {
            float a = acc[j];
#pragma unroll
            for (int ii = 0; ii < 32; ++ii)
                a += hv[ii] * W1blk[j * 128 + ii];
            acc[j] = a;
        }
    }
}

__global__ __launch_bounds__(256) void gather_mlp(
    const int* __restrict__ idx2, const int* __restrict__ idx3,
    const int* __restrict__ idx4,
    const int* __restrict__ offs2, const int* __restrict__ offs3,
    const int* __restrict__ offs4,
    const int* __restrict__ ent2, const int* __restrict__ ent3,
    const int* __restrict__ ent4,
    const float* __restrict__ G, const float* __restrict__ Whh,
    const float* __restrict__ bhh,
    const float* __restrict__ h,
    const float* __restrict__ W1, const float* __restrict__ b1,
    const float* __restrict__ W2, const float* __restrict__ b2,
    float* __restrict__ out, int n1)
{
    int node = blockIdx.x * 256 + threadIdx.x;
    if (node >= n1) return;

    float acc[32];
    {
        float xr[32];
        const float4* hx = (const float4*)(h + (size_t)node * 32);
#pragma unroll
        for (int c = 0; c < 8; ++c) {
            float4 v = hx[c];
            xr[c*4+0] = v.x; xr[c*4+1] = v.y; xr[c*4+2] = v.z; xr[c*4+3] = v.w;
        }
#pragma unroll
        for (int j = 0; j < 32; ++j) {
            float a = b1[j];
#pragma unroll
            for (int i = 0; i < 32; ++i)
                a += xr[i] * W1[j * 128 + i];
            acc[j] = a;
        }
    }

    seg_fold<2>(idx2, offs2, ent2, node, G, Whh, bhh, W1 + 32, acc);
    seg_fold<3>(idx3, offs3, ent3, node, G, Whh, bhh, W1 + 64, acc);
    seg_fold<4>(idx4, offs4, ent4, node, G, Whh, bhh, W1 + 96, acc);

    float tv[32];
#pragma unroll
    for (int j = 0; j < 32; ++j) tv[j] = tanhf_(acc[j]);

    float* orow = out + (size_t)node * 32;
#pragma unroll
    for (int ob = 0; ob < 8; ++ob) {
        float o[4];
#pragma unroll
        for (int q = 0; q < 4; ++q) {
            int oj = ob * 4 + q;
            float a = b2[oj];
#pragma unroll
            for (int j = 0; j < 32; ++j)
                a += tv[j] * W2[oj * 32 + j];
            o[q] = a;
        }
        *(float4*)(orow + ob * 4) = make_float4(o[0], o[1], o[2], o[3]);
    }
}

// ---------------------------------------------------------------------------
// Fallback kernels (atomic scatter + separate MLP) — used only if ws too small
// ---------------------------------------------------------------------------
template <int K>
__global__ __launch_bounds__(256) void gru_edges_atomic(
    const int* __restrict__ idx, int nE,
    const float* __restrict__ G,
    const float* __restrict__ Whh, const float* __restrict__ bhh,
    float* __restrict__ hk)
{
    int e = blockIdx.x * 256 + threadIdx.x;
    if (e >= nE) return;
    float hv[32];
#pragma unroll
    for (int t = 0; t < K; ++t) {
        int node = idx[(size_t)e * K + t];
        const float* grow = G + (size_t)node * 96;
        float hn_[32];
#pragma unroll
        for (int jb = 0; jb < 8; ++jb) {
            float4 gr4 = *(const float4*)(grow + jb * 4);
            float4 gz4 = *(const float4*)(grow + 32 + jb * 4);
            float4 gn4 = *(const float4*)(grow + 64 + jb * 4);
#pragma unroll
            for (int q = 0; q < 4; ++q) {
                int j = jb * 4 + q;
                float ir = f4c(gr4, q), iz = f4c(gz4, q), in_ = f4c(gn4, q);
                float hr = bhh[j], hz = bhh[32 + j], hn2 = bhh[64 + j];
                if (t > 0) {
#pragma unroll
                    for (int i = 0; i < 32; ++i) {
                        hr  += hv[i] * Whh[j * 32 + i];
                        hz  += hv[i] * Whh[(32 + j) * 32 + i];
                        hn2 += hv[i] * Whh[(64 + j) * 32 + i];
                    }
                }
                float r = sigmoidf_(ir + hr);
                float z = sigmoidf_(iz + hz);
                float n = tanhf_(in_ + r * hn2);
                hn_[j] = (t > 0) ? ((1.0f - z) * n + z * hv[j]) : (1.0f - z) * n;
            }
        }
        float* dst = hk + (size_t)node * 32;
#pragma unroll
        for (int j = 0; j < 32; ++j) {
            hv[j] = hn_[j];
            atomicAdd(dst + j, hn_[j]);
        }
    }
}

__global__ __launch_bounds__(256) void mlp_out(
    const float* __restrict__ h, const float* __restrict__ hk, int n1,
    const float* __restrict__ W1, const float* __restrict__ b1,
    const float* __restrict__ W2, const float* __restrict__ b2,
    float* __restrict__ out)
{
    int node = blockIdx.x * 256 + threadIdx.x;
    if (node >= n1) return;
    float acc[32];
#pragma unroll
    for (int j = 0; j < 32; ++j) acc[j] = b1[j];
    const float* zsrc[4];
    zsrc[0] = h + (size_t)node * 32;
    zsrc[1] = hk + (size_t)node * 32;
    zsrc[2] = hk + (size_t)n1 * 32 + (size_t)node * 32;
    zsrc[3] = hk + (size_t)n1 * 64 + (size_t)node * 32;
#pragma unroll
    for (int m = 0; m < 4; ++m) {
        float zc[32];
        const float4* zp = (const float4*)zsrc[m];
#pragma unroll
        for (int c = 0; c < 8; ++c) {
            float4 v = zp[c];
            zc[c*4+0] = v.x; zc[c*4+1] = v.y; zc[c*4+2] = v.z; zc[c*4+3] = v.w;
        }
#pragma unroll
        for (int j = 0; j < 32; ++j) {
#pragma unroll
            for (int i = 0; i < 32; ++i)
                acc[j] += zc[i] * W1[j * 128 + m * 32 + i];
        }
    }
    float tv[32];
#pragma unroll
    for (int j = 0; j < 32; ++j) tv[j] = tanhf_(acc[j]);
    float* orow = out + (size_t)node * 32;
#pragma unroll
    for (int ob = 0; ob < 8; ++ob) {
        float o[4];
#pragma unroll
        for (int q = 0; q < 4; ++q) {
            int oj = ob * 4 + q;
            float a = b2[oj];
#pragma unroll
            for (int j = 0; j < 32; ++j)
                a += tv[j] * W2[oj * 32 + j];
            o[q] = a;
        }
        *(float4*)(orow + ob * 4) = make_float4(o[0], o[1], o[2], o[3]);
    }
}

// ---------------------------------------------------------------------------
static inline size_t alignUp(size_t x, size_t a) { return (x + a - 1) & ~(a - 1); }

extern "C" void kernel_launch(void* const* d_in, const int* in_sizes, int n_in,
                              void* d_out, int out_size, void* d_ws, size_t ws_size,
                              hipStream_t stream)
{
    const float* h    = (const float*)d_in[0];
    const int*   idx2 = (const int*)d_in[1];
    const int*   idx3 = (const int*)d_in[2];
    const int*   idx4 = (const int*)d_in[3];
    const float* Wih  = (const float*)d_in[4];
    const float* Whh  = (const float*)d_in[5];
    const float* bih  = (const float*)d_in[6];
    const float* bhh  = (const float*)d_in[7];
    const float* W1   = (const float*)d_in[8];
    const float* b1   = (const float*)d_in[9];
    const float* W2   = (const float*)d_in[10];
    const float* b2   = (const float*)d_in[11];
    float* out = (float*)d_out;

    int n1 = in_sizes[0] / 32;
    int n2 = in_sizes[1] / 2;
    int n3 = in_sizes[2] / 3;
    int n4 = in_sizes[3] / 4;

    int nI2 = n2 * 2, nI3 = n3 * 3, nI4 = n4 * 4;

    // ---- workspace layout (all aligned 256B) ----
    size_t off = 0;
    size_t gOff    = off; off = alignUp(off + (size_t)n1 * 96 * 4, 256);
    size_t e2Off   = off; off = alignUp(off + (size_t)nI2 * 4, 256);
    size_t e3Off   = off; off = alignUp(off + (size_t)nI3 * 4, 256);
    size_t e4Off   = off; off = alignUp(off + (size_t)nI4 * 4, 256);
    size_t o2Off   = off; off = alignUp(off + ((size_t)n1 + 1) * 4, 256);
    size_t o3Off   = off; off = alignUp(off + ((size_t)n1 + 1) * 4, 256);
    size_t o4Off   = off; off = alignUp(off + ((size_t)n1 + 1) * 4, 256);
    size_t cntOff  = off; off = alignUp(off + (size_t)n1 * 4, 256);
    size_t inclOff = off; off = alignUp(off + (size_t)n1 * 4, 256);
    size_t curOff  = off; off = alignUp(off + (size_t)n1 * 4, 256);
    size_t bsumOff = off; off = alignUp(off + 4096, 256);
    size_t need = off;

    char* ws = (char*)d_ws;
    int blocksN1 = (n1 + 255) / 256;
    int nScanBlocks = (n1 + 255) / 256;   // 782 for n1=200k, fits 1024-scan

    if (ws_size >= need && nScanBlocks <= 1024) {
        float* G    = (float*)(ws + gOff);
        int* ent[3] = { (int*)(ws + e2Off), (int*)(ws + e3Off), (int*)(ws + e4Off) };
        int* offs[3]= { (int*)(ws + o2Off), (int*)(ws + o3Off), (int*)(ws + o4Off) };
        int* count  = (int*)(ws + cntOff);
        int* incl   = (int*)(ws + inclOff);
        int* cursor = (int*)(ws + curOff);
        int* bsums  = (int*)(ws + bsumOff);

        precompute_gi<<<blocksN1, 256, 0, stream>>>(h, Wih, bih, G, n1);

        const int* idxs[3] = { idx2, idx3, idx4 };
        int nIs[3] = { nI2, nI3, nI4 };
        for (int kk = 0; kk < 3; ++kk) {
            int nI = nIs[kk];
            hipMemsetAsync(count, 0, (size_t)n1 * 4, stream);
            hist_kernel<<<(nI + 255) / 256, 256, 0, stream>>>(idxs[kk], nI, count);
            scan_block<<<nScanBlocks, 256, 0, stream>>>(count, incl, bsums, n1);
            scan_bsums<<<1, 1024, 0, stream>>>(bsums, nScanBlocks);
            finalize_offs<<<nScanBlocks, 256, 0, stream>>>(incl, bsums, offs[kk], n1);
            hipMemcpyAsync(cursor, offs[kk], (size_t)n1 * 4,
                           hipMemcpyDeviceToDevice, stream);
            fill_entries<<<(nI + 255) / 256, 256, 0, stream>>>(
                idxs[kk], nI, cursor, ent[kk]);
        }

        gather_mlp<<<blocksN1, 256, 0, stream>>>(
            idx2, idx3, idx4, offs[0], offs[1], offs[2],
            ent[0], ent[1], ent[2], G, Whh, bhh, h, W1, b1, W2, b2, out, n1);
        return;
    }

    // ===== fallback: atomic path (requires hk+G = n1*192*4 bytes) =====
    float* hk = (float*)d_ws;
    float* G  = (float*)((char*)d_ws + (size_t)n1 * 96 * 4);
    hipMemsetAsync(d_ws, 0, (size_t)n1 * 96 * 4, stream);
    precompute_gi<<<blocksN1, 256, 0, stream>>>(h, Wih, bih, G, n1);
    gru_edges_atomic<2><<<(n2 + 255) / 256, 256, 0, stream>>>(
        idx2, n2, G, Whh, bhh, hk);
    gru_edges_atomic<3><<<(n3 + 255) / 256, 256, 0, stream>>>(
        idx3, n3, G, Whh, bhh, hk + (size_t)n1 * 32);
    gru_edges_atomic<4><<<(n4 + 255) / 256, 256, 0, stream>>>(
        idx4, n4, G, Whh, bhh, hk + (size_t)n1 * 64);
    mlp_out<<<blocksN1, 256, 0, stream>>>(h, hk, n1, W1, b1, W2, b2, out);
}

// Round 5
// 2159.405 us; speedup vs baseline: 4.6405x; 4.6405x over previous
//
#include <hip/hip_runtime.h>
#include <hip/hip_bf16.h>

__device__ __forceinline__ float sigmoidf_(float x) {
    return 1.0f / (1.0f + __expf(-x));
}
__device__ __forceinline__ float tanhf_(float x) {
    float e = __expf(2.0f * x);
    return 1.0f - 2.0f / (e + 1.0f);
}
__device__ __forceinline__ float f4c(const float4& v, int q) {
    return q == 0 ? v.x : q == 1 ? v.y : q == 2 ? v.z : v.w;
}

// ---------------------------------------------------------------------------
// G[node, 0..95] = h[node] @ Wih.T + bih   (Tier-1 only)
// ---------------------------------------------------------------------------
__global__ __launch_bounds__(256) void precompute_gi(
    const float* __restrict__ h, const float* __restrict__ Wih,
    const float* __restrict__ bih, float* __restrict__ G, int n1)
{
    int node = blockIdx.x * 256 + threadIdx.x;
    if (node >= n1) return;
    float x[32];
    const float4* hx = (const float4*)(h + (size_t)node * 32);
#pragma unroll
    for (int c = 0; c < 8; ++c) {
        float4 v = hx[c];
        x[c*4+0] = v.x; x[c*4+1] = v.y; x[c*4+2] = v.z; x[c*4+3] = v.w;
    }
    float* grow = G + (size_t)node * 96;
#pragma unroll
    for (int jb = 0; jb < 24; ++jb) {
        float acc[4];
#pragma unroll
        for (int q = 0; q < 4; ++q) {
            int j = jb * 4 + q;
            float a = bih[j];
#pragma unroll
            for (int i = 0; i < 32; ++i)
                a += x[i] * Wih[j * 32 + i];
            acc[q] = a;
        }
        *(float4*)(grow + jb * 4) = make_float4(acc[0], acc[1], acc[2], acc[3]);
    }
}

// ---------------------------------------------------------------------------
// CSR build over column t of idx (stride K)
// ---------------------------------------------------------------------------
template <int K>
__global__ __launch_bounds__(256) void hist_col(
    const int* __restrict__ idx, int nE, int t, int* __restrict__ count)
{
    int e = blockIdx.x * 256 + threadIdx.x;
    if (e < nE) atomicAdd(&count[idx[(size_t)e * K + t]], 1);
}

__global__ __launch_bounds__(256) void scan_block(
    const int* __restrict__ count, int* __restrict__ incl,
    int* __restrict__ bsums, int n)
{
    __shared__ int s[256];
    int i = blockIdx.x * 256 + threadIdx.x;
    int v = (i < n) ? count[i] : 0;
    s[threadIdx.x] = v;
    __syncthreads();
    for (int d = 1; d < 256; d <<= 1) {
        int tt = (threadIdx.x >= d) ? s[threadIdx.x - d] : 0;
        __syncthreads();
        s[threadIdx.x] += tt;
        __syncthreads();
    }
    if (i < n) incl[i] = s[threadIdx.x];
    if (threadIdx.x == 255) bsums[blockIdx.x] = s[255];
}

__global__ __launch_bounds__(1024) void scan_bsums(int* bsums, int nb)
{
    __shared__ int s[1024];
    int v = (threadIdx.x < nb) ? bsums[threadIdx.x] : 0;
    s[threadIdx.x] = v;
    __syncthreads();
    for (int d = 1; d < 1024; d <<= 1) {
        int tt = (threadIdx.x >= d) ? s[threadIdx.x - d] : 0;
        __syncthreads();
        s[threadIdx.x] += tt;
        __syncthreads();
    }
    if (threadIdx.x < nb) bsums[threadIdx.x] = s[threadIdx.x] - v; // exclusive
}

__global__ __launch_bounds__(256) void finalize_offs(
    const int* __restrict__ incl, const int* __restrict__ bsums,
    int* __restrict__ offs, int n)
{
    int i = blockIdx.x * 256 + threadIdx.x;
    if (i < n) offs[i + 1] = incl[i] + bsums[blockIdx.x];
    if (i == 0) offs[0] = 0;
}

template <int K>
__global__ __launch_bounds__(256) void fill_col(
    const int* __restrict__ idx, int nE, int t,
    int* __restrict__ cursor, int* __restrict__ entries)
{
    int e = blockIdx.x * 256 + threadIdx.x;
    if (e >= nE) return;
    int n = idx[(size_t)e * K + t];
    int p = atomicAdd(&cursor[n], 1);
    entries[p] = e;
}

// ---------------------------------------------------------------------------
// One GRU step for all edges of a k-list. hstate[e] = h_{t} (in/out).
// Balanced: every thread does the same work. No atomics.
// ---------------------------------------------------------------------------
template <int K, bool USE_G>
__global__ __launch_bounds__(256) void gru_step(
    const int* __restrict__ idx, int nE, int t,
    const float* __restrict__ G, const float* __restrict__ h,
    const float* __restrict__ Wih, const float* __restrict__ bih,
    const float* __restrict__ Whh, const float* __restrict__ bhh,
    float* __restrict__ hstate)
{
    int e = blockIdx.x * 256 + threadIdx.x;
    if (e >= nE) return;
    int node = idx[(size_t)e * K + t];

    float hv[32];
    if (t > 0) {
        const float4* hs = (const float4*)(hstate + (size_t)e * 32);
#pragma unroll
        for (int c = 0; c < 8; ++c) {
            float4 v = hs[c];
            hv[c*4+0] = v.x; hv[c*4+1] = v.y; hv[c*4+2] = v.z; hv[c*4+3] = v.w;
        }
    }

    float x[32];
    const float* grow = G + (size_t)node * 96;
    if (!USE_G) {
        const float4* hx = (const float4*)(h + (size_t)node * 32);
#pragma unroll
        for (int c = 0; c < 8; ++c) {
            float4 v = hx[c];
            x[c*4+0] = v.x; x[c*4+1] = v.y; x[c*4+2] = v.z; x[c*4+3] = v.w;
        }
    }

    float hn[32];
#pragma unroll
    for (int jb = 0; jb < 8; ++jb) {
        float4 gr4, gz4, gn4;
        if (USE_G) {
            gr4 = *(const float4*)(grow + jb * 4);
            gz4 = *(const float4*)(grow + 32 + jb * 4);
            gn4 = *(const float4*)(grow + 64 + jb * 4);
        }
#pragma unroll
        for (int q = 0; q < 4; ++q) {
            int j = jb * 4 + q;
            float ir, iz, in_;
            if (USE_G) {
                ir = f4c(gr4, q); iz = f4c(gz4, q); in_ = f4c(gn4, q);
            } else {
                ir = bih[j]; iz = bih[32 + j]; in_ = bih[64 + j];
#pragma unroll
                for (int i = 0; i < 32; ++i) {
                    ir  += x[i] * Wih[j * 32 + i];
                    iz  += x[i] * Wih[(32 + j) * 32 + i];
                    in_ += x[i] * Wih[(64 + j) * 32 + i];
                }
            }
            float hr = bhh[j], hz = bhh[32 + j], hn2 = bhh[64 + j];
            if (t > 0) {
#pragma unroll
                for (int i = 0; i < 32; ++i) {
                    hr  += hv[i] * Whh[j * 32 + i];
                    hz  += hv[i] * Whh[(32 + j) * 32 + i];
                    hn2 += hv[i] * Whh[(64 + j) * 32 + i];
                }
            }
            float r = sigmoidf_(ir + hr);
            float z = sigmoidf_(iz + hz);
            float n = tanhf_(in_ + r * hn2);
            hn[j] = (t > 0) ? ((1.0f - z) * n + z * hv[j]) : (1.0f - z) * n;
        }
    }
    float4* hs = (float4*)(hstate + (size_t)e * 32);
#pragma unroll
    for (int c = 0; c < 8; ++c)
        hs[c] = make_float4(hn[c*4+0], hn[c*4+1], hn[c*4+2], hn[c*4+3]);
}

// ---------------------------------------------------------------------------
// hkk[node] += sum over CSR entries of hstate[e] rows. 8 threads/node.
// Owner-exclusive: no atomics.
// ---------------------------------------------------------------------------
__global__ __launch_bounds__(256) void gather_add(
    const int* __restrict__ offs, const int* __restrict__ ent,
    const float* __restrict__ hstate, float* __restrict__ hkk, int n1)
{
    int gid = blockIdx.x * 256 + threadIdx.x;
    int node = gid >> 3;
    int sub = gid & 7;
    if (node >= n1) return;
    int beg = offs[node], end = offs[node + 1];
    if (beg == end) return;
    float4 a = make_float4(0.f, 0.f, 0.f, 0.f);
    for (int p = beg; p < end; ++p) {
        int e = ent[p];
        float4 v = *(const float4*)(hstate + (size_t)e * 32 + sub * 4);
        a.x += v.x; a.y += v.y; a.z += v.z; a.w += v.w;
    }
    float* dst = hkk + (size_t)node * 32 + sub * 4;
    float4 cur = *(float4*)dst;
    cur.x += a.x; cur.y += a.y; cur.z += a.z; cur.w += a.w;
    *(float4*)dst = cur;
}

// ---------------------------------------------------------------------------
// acc[node] = b1 + h[node] @ W1[:, 0:32].T
// ---------------------------------------------------------------------------
__global__ __launch_bounds__(256) void init_acc(
    const float* __restrict__ h, const float* __restrict__ W1,
    const float* __restrict__ b1, float* __restrict__ acc, int n1)
{
    int node = blockIdx.x * 256 + threadIdx.x;
    if (node >= n1) return;
    float x[32];
    const float4* hx = (const float4*)(h + (size_t)node * 32);
#pragma unroll
    for (int c = 0; c < 8; ++c) {
        float4 v = hx[c];
        x[c*4+0] = v.x; x[c*4+1] = v.y; x[c*4+2] = v.z; x[c*4+3] = v.w;
    }
    float* arow = acc + (size_t)node * 32;
#pragma unroll
    for (int jb = 0; jb < 8; ++jb) {
        float o[4];
#pragma unroll
        for (int q = 0; q < 4; ++q) {
            int j = jb * 4 + q;
            float a = b1[j];
#pragma unroll
            for (int i = 0; i < 32; ++i)
                a += x[i] * W1[j * 128 + i];
            o[q] = a;
        }
        *(float4*)(arow + jb * 4) = make_float4(o[0], o[1], o[2], o[3]);
    }
}

// ---------------------------------------------------------------------------
// acc[node] += hkk[node] @ W1blk.T   (W1blk = W1 + m*32, row stride 128)
// ---------------------------------------------------------------------------
__global__ __launch_bounds__(256) void fold_w1(
    const float* __restrict__ hkk, const float* __restrict__ W1blk,
    float* __restrict__ acc, int n1)
{
    int node = blockIdx.x * 256 + threadIdx.x;
    if (node >= n1) return;
    float x[32];
    const float4* hx = (const float4*)(hkk + (size_t)node * 32);
#pragma unroll
    for (int c = 0; c < 8; ++c) {
        float4 v = hx[c];
        x[c*4+0] = v.x; x[c*4+1] = v.y; x[c*4+2] = v.z; x[c*4+3] = v.w;
    }
    float* arow = acc + (size_t)node * 32;
#pragma unroll
    for (int jb = 0; jb < 8; ++jb) {
        float4 cur = *(float4*)(arow + jb * 4);
        float o[4] = { cur.x, cur.y, cur.z, cur.w };
#pragma unroll
        for (int q = 0; q < 4; ++q) {
            int j = jb * 4 + q;
            float a = o[q];
#pragma unroll
            for (int i = 0; i < 32; ++i)
                a += x[i] * W1blk[j * 128 + i];
            o[q] = a;
        }
        *(float4*)(arow + jb * 4) = make_float4(o[0], o[1], o[2], o[3]);
    }
}

// ---------------------------------------------------------------------------
// out[node] = tanh(acc[node]) @ W2.T + b2
// ---------------------------------------------------------------------------
__global__ __launch_bounds__(256) void finish_out(
    const float* __restrict__ acc, const float* __restrict__ W2,
    const float* __restrict__ b2, float* __restrict__ out, int n1)
{
    int node = blockIdx.x * 256 + threadIdx.x;
    if (node >= n1) return;
    float tv[32];
    const float4* ax = (const float4*)(acc + (size_t)node * 32);
#pragma unroll
    for (int c = 0; c < 8; ++c) {
        float4 v = ax[c];
        tv[c*4+0] = tanhf_(v.x); tv[c*4+1] = tanhf_(v.y);
        tv[c*4+2] = tanhf_(v.z); tv[c*4+3] = tanhf_(v.w);
    }
    float* orow = out + (size_t)node * 32;
#pragma unroll
    for (int ob = 0; ob < 8; ++ob) {
        float o[4];
#pragma unroll
        for (int q = 0; q < 4; ++q) {
            int oj = ob * 4 + q;
            float a = b2[oj];
#pragma unroll
            for (int j = 0; j < 32; ++j)
                a += tv[j] * W2[oj * 32 + j];
            o[q] = a;
        }
        *(float4*)(orow + ob * 4) = make_float4(o[0], o[1], o[2], o[3]);
    }
}

// ---------------------------------------------------------------------------
// Fallback: atomic scatter without G (needs only hk = n1*96*4 bytes)
// ---------------------------------------------------------------------------
template <int K>
__global__ __launch_bounds__(256) void gru_edges_atomic_noG(
    const int* __restrict__ idx, int nE,
    const float* __restrict__ h,
    const float* __restrict__ Wih, const float* __restrict__ bih,
    const float* __restrict__ Whh, const float* __restrict__ bhh,
    float* __restrict__ hk)
{
    int e = blockIdx.x * 256 + threadIdx.x;
    if (e >= nE) return;
    float hv[32];
#pragma unroll
    for (int t = 0; t < K; ++t) {
        int node = idx[(size_t)e * K + t];
        float x[32];
        const float4* hx = (const float4*)(h + (size_t)node * 32);
#pragma unroll
        for (int c = 0; c < 8; ++c) {
            float4 v = hx[c];
            x[c*4+0] = v.x; x[c*4+1] = v.y; x[c*4+2] = v.z; x[c*4+3] = v.w;
        }
        float hn_[32];
#pragma unroll
        for (int j = 0; j < 32; ++j) {
            float ir = bih[j], iz = bih[32 + j], in_ = bih[64 + j];
#pragma unroll
            for (int i = 0; i < 32; ++i) {
                ir  += x[i] * Wih[j * 32 + i];
                iz  += x[i] * Wih[(32 + j) * 32 + i];
                in_ += x[i] * Wih[(64 + j) * 32 + i];
            }
            float hr = bhh[j], hz = bhh[32 + j], hn2 = bhh[64 + j];
            if (t > 0) {
#pragma unroll
                for (int i = 0; i < 32; ++i) {
                    hr  += hv[i] * Whh[j * 32 + i];
                    hz  += hv[i] * Whh[(32 + j) * 32 + i];
                    hn2 += hv[i] * Whh[(64 + j) * 32 + i];
                }
            }
            float r = sigmoidf_(ir + hr);
            float z = sigmoidf_(iz + hz);
            float n = tanhf_(in_ + r * hn2);
            hn_[j] = (t > 0) ? ((1.0f - z) * n + z * hv[j]) : (1.0f - z) * n;
        }
        float* dst = hk + (size_t)node * 32;
#pragma unroll
        for (int j = 0; j < 32; ++j) {
            hv[j] = hn_[j];
            atomicAdd(dst + j, hn_[j]);
        }
    }
}

__global__ __launch_bounds__(256) void mlp_out_fb(
    const float* __restrict__ h, const float* __restrict__ hk, int n1,
    const float* __restrict__ W1, const float* __restrict__ b1,
    const float* __restrict__ W2, const float* __restrict__ b2,
    float* __restrict__ out)
{
    int node = blockIdx.x * 256 + threadIdx.x;
    if (node >= n1) return;
    float acc[32];
#pragma unroll
    for (int j = 0; j < 32; ++j) acc[j] = b1[j];
    const float* zsrc[4];
    zsrc[0] = h + (size_t)node * 32;
    zsrc[1] = hk + (size_t)node * 32;
    zsrc[2] = hk + (size_t)n1 * 32 + (size_t)node * 32;
    zsrc[3] = hk + (size_t)n1 * 64 + (size_t)node * 32;
#pragma unroll
    for (int m = 0; m < 4; ++m) {
        float zc[32];
        const float4* zp = (const float4*)zsrc[m];
#pragma unroll
        for (int c = 0; c < 8; ++c) {
            float4 v = zp[c];
            zc[c*4+0] = v.x; zc[c*4+1] = v.y; zc[c*4+2] = v.z; zc[c*4+3] = v.w;
        }
#pragma unroll
        for (int j = 0; j < 32; ++j) {
#pragma unroll
            for (int i = 0; i < 32; ++i)
                acc[j] += zc[i] * W1[j * 128 + m * 32 + i];
        }
    }
    float tv[32];
#pragma unroll
    for (int j = 0; j < 32; ++j) tv[j] = tanhf_(acc[j]);
    float* orow = out + (size_t)node * 32;
#pragma unroll
    for (int ob = 0; ob < 8; ++ob) {
        float o[4];
#pragma unroll
        for (int q = 0; q < 4; ++q) {
            int oj = ob * 4 + q;
            float a = b2[oj];
#pragma unroll
            for (int j = 0; j < 32; ++j)
                a += tv[j] * W2[oj * 32 + j];
            o[q] = a;
        }
        *(float4*)(orow + ob * 4) = make_float4(o[0], o[1], o[2], o[3]);
    }
}

// ---------------------------------------------------------------------------
static inline size_t alignUp(size_t x, size_t a) { return (x + a - 1) & ~(a - 1); }

extern "C" void kernel_launch(void* const* d_in, const int* in_sizes, int n_in,
                              void* d_out, int out_size, void* d_ws, size_t ws_size,
                              hipStream_t stream)
{
    const float* h    = (const float*)d_in[0];
    const int*   idx2 = (const int*)d_in[1];
    const int*   idx3 = (const int*)d_in[2];
    const int*   idx4 = (const int*)d_in[3];
    const float* Wih  = (const float*)d_in[4];
    const float* Whh  = (const float*)d_in[5];
    const float* bih  = (const float*)d_in[6];
    const float* bhh  = (const float*)d_in[7];
    const float* W1   = (const float*)d_in[8];
    const float* b1   = (const float*)d_in[9];
    const float* W2   = (const float*)d_in[10];
    const float* b2   = (const float*)d_in[11];
    float* out = (float*)d_out;

    int n1 = in_sizes[0] / 32;
    int n2 = in_sizes[1] / 2;
    int n3 = in_sizes[2] / 3;
    int n4 = in_sizes[3] / 4;
    int nEmax = n2 > n3 ? n2 : n3; if (n4 > nEmax) nEmax = n4;

    // ---- workspace layout ----
    size_t off = 0;
    size_t hsOff   = off; off = alignUp(off + (size_t)nEmax * 32 * 4, 256);
    size_t accOff  = off; off = alignUp(off + (size_t)n1 * 32 * 4, 256);
    size_t hkkOff  = off; off = alignUp(off + (size_t)n1 * 32 * 4, 256);
    size_t entOff  = off; off = alignUp(off + (size_t)nEmax * 4, 256);
    size_t offsOff = off; off = alignUp(off + ((size_t)n1 + 1) * 4, 256);
    size_t cntOff  = off; off = alignUp(off + (size_t)n1 * 4, 256);
    size_t inclOff = off; off = alignUp(off + (size_t)n1 * 4, 256);
    size_t curOff  = off; off = alignUp(off + (size_t)n1 * 4, 256);
    size_t bsumOff = off; off = alignUp(off + 4096, 256);
    size_t need2 = off;                                   // Tier-2 (no G)
    size_t gOff    = off; off = alignUp(off + (size_t)n1 * 96 * 4, 256);
    size_t need1 = off;                                   // Tier-1 (with G)

    int blocksN1 = (n1 + 255) / 256;
    int nScanBlocks = (n1 + 255) / 256;
    char* ws = (char*)d_ws;

    if (ws_size >= need2 && nScanBlocks <= 1024) {
        bool useG = (ws_size >= need1);
        float* hstate = (float*)(ws + hsOff);
        float* acc    = (float*)(ws + accOff);
        float* hkk    = (float*)(ws + hkkOff);
        int*   ent    = (int*)(ws + entOff);
        int*   offs   = (int*)(ws + offsOff);
        int*   count  = (int*)(ws + cntOff);
        int*   incl   = (int*)(ws + inclOff);
        int*   cursor = (int*)(ws + curOff);
        int*   bsums  = (int*)(ws + bsumOff);
        float* G      = useG ? (float*)(ws + gOff) : nullptr;

        if (useG)
            precompute_gi<<<blocksN1, 256, 0, stream>>>(h, Wih, bih, G, n1);
        init_acc<<<blocksN1, 256, 0, stream>>>(h, W1, b1, acc, n1);

        const int* idxs[3] = { idx2, idx3, idx4 };
        int nEs[3] = { n2, n3, n4 };

        for (int kk = 0; kk < 3; ++kk) {
            const int* idx = idxs[kk];
            int nE = nEs[kk];
            int K = kk + 2;
            int blocksE = (nE + 255) / 256;

            hipMemsetAsync(hkk, 0, (size_t)n1 * 32 * 4, stream);

            for (int t = 0; t < K; ++t) {
                // CSR for column t
                hipMemsetAsync(count, 0, (size_t)n1 * 4, stream);
                if (K == 2)      hist_col<2><<<blocksE, 256, 0, stream>>>(idx, nE, t, count);
                else if (K == 3) hist_col<3><<<blocksE, 256, 0, stream>>>(idx, nE, t, count);
                else             hist_col<4><<<blocksE, 256, 0, stream>>>(idx, nE, t, count);
                scan_block<<<nScanBlocks, 256, 0, stream>>>(count, incl, bsums, n1);
                scan_bsums<<<1, 1024, 0, stream>>>(bsums, nScanBlocks);
                finalize_offs<<<nScanBlocks, 256, 0, stream>>>(incl, bsums, offs, n1);
                hipMemcpyAsync(cursor, offs, (size_t)n1 * 4,
                               hipMemcpyDeviceToDevice, stream);
                if (K == 2)      fill_col<2><<<blocksE, 256, 0, stream>>>(idx, nE, t, cursor, ent);
                else if (K == 3) fill_col<3><<<blocksE, 256, 0, stream>>>(idx, nE, t, cursor, ent);
                else             fill_col<4><<<blocksE, 256, 0, stream>>>(idx, nE, t, cursor, ent);

                // advance GRU one step for all edges
                if (useG) {
                    if (K == 2)      gru_step<2, true><<<blocksE, 256, 0, stream>>>(idx, nE, t, G, h, Wih, bih, Whh, bhh, hstate);
                    else if (K == 3) gru_step<3, true><<<blocksE, 256, 0, stream>>>(idx, nE, t, G, h, Wih, bih, Whh, bhh, hstate);
                    else             gru_step<4, true><<<blocksE, 256, 0, stream>>>(idx, nE, t, G, h, Wih, bih, Whh, bhh, hstate);
                } else {
                    if (K == 2)      gru_step<2, false><<<blocksE, 256, 0, stream>>>(idx, nE, t, G, h, Wih, bih, Whh, bhh, hstate);
                    else if (K == 3) gru_step<3, false><<<blocksE, 256, 0, stream>>>(idx, nE, t, G, h, Wih, bih, Whh, bhh, hstate);
                    else             gru_step<4, false><<<blocksE, 256, 0, stream>>>(idx, nE, t, G, h, Wih, bih, Whh, bhh, hstate);
                }

                // owner-side accumulate (no atomics)
                gather_add<<<((n1 * 8) + 255) / 256, 256, 0, stream>>>(
                    offs, ent, hstate, hkk, n1);
            }

            fold_w1<<<blocksN1, 256, 0, stream>>>(hkk, W1 + (kk + 1) * 32, acc, n1);
        }

        finish_out<<<blocksN1, 256, 0, stream>>>(acc, W2, b2, out, n1);
        return;
    }

    // ===== fallback: atomic path, hk only (n1*96*4 bytes) =====
    float* hk = (float*)d_ws;
    hipMemsetAsync(d_ws, 0, (size_t)n1 * 96 * 4, stream);
    gru_edges_atomic_noG<2><<<(n2 + 255) / 256, 256, 0, stream>>>(
        idx2, n2, h, Wih, bih, Whh, bhh, hk);
    gru_edges_atomic_noG<3><<<(n3 + 255) / 256, 256, 0, stream>>>(
        idx3, n3, h, Wih, bih, Whh, bhh, hk + (size_t)n1 * 32);
    gru_edges_atomic_noG<4><<<(n4 + 255) / 256, 256, 0, stream>>>(
        idx4, n4, h, Wih, bih, Whh, bhh, hk + (size_t)n1 * 64);
    mlp_out_fb<<<blocksN1, 256, 0, stream>>>(h, hk, n1, W1, b1, W2, b2, out);
}